// Round 10
// baseline (794.661 us; speedup 1.0000x reference)
//
#include <hip/hip_runtime.h>
#include <hip/hip_cooperative_groups.h>
#include <math.h>

namespace cg = cooperative_groups;

#define B_ 4
#define C_ 8
#define H_ 192
#define W_ 256
#define HW_ (H_*W_)
#define GEOMW 0.01f
#define HUBER 0.5f
#define LMEPS 1e-6f

// ws layout (floats)
#define N0_SZ  (B_*3*HW_)
#define ACC_SZ (3*B_*32)
#define POSE_SZ (B_*16)

typedef float f4a __attribute__((ext_vector_type(4), aligned(4)));
typedef float f2a __attribute__((ext_vector_type(2), aligned(4)));

// ---------- shared device helpers ----------

__device__ __forceinline__ void compute_normal(const float* __restrict__ d,
                                               float fx, float fy, float cx, float cy,
                                               int p, float* nx, float* ny, float* nz) {
    const int h = p >> 8, w = p & 255;
    const int wl = max(w-1, 0), wr = min(w+1, W_-1);
    const int hu = max(h-1, 0), hd = min(h+1, H_-1);
    const float dr = d[h*W_ + wr], dl = d[h*W_ + wl];
    const float dd = d[hd*W_ + w], du_ = d[hu*W_ + w];
    const float pxr = ((float)wr - cx)/fx, pxl = ((float)wl - cx)/fx;
    const float pyh = ((float)h  - cy)/fy;
    const float pxw = ((float)w  - cx)/fx;
    const float pyd = ((float)hd - cy)/fy, pyu = ((float)hu - cy)/fy;
    const float dxx = 0.5f*(pxr*dr - pxl*dl), dxy = 0.5f*(pyh*dr - pyh*dl), dxz = 0.5f*(dr - dl);
    const float dyx = 0.5f*(pxw*dd - pxw*du_), dyy = 0.5f*(pyd*dd - pyu*du_), dyz = 0.5f*(dd - du_);
    const float n0 = dxy*dyz - dxz*dyy;
    const float n1 = dxz*dyx - dxx*dyz;
    const float n2 = dxx*dyy - dxy*dyx;
    const float inv = 1.0f / sqrtf(n0*n0 + n1*n1 + n2*n2 + 1e-12f);
    *nx = n0*inv; *ny = n1*inv; *nz = n2*inv;
}

// accumulate one thread's items into a[27]; EXACT r8 hot-loop body.
__device__ __forceinline__ void accum_items(
        const float* __restrict__ I0b, const float* __restrict__ I1b,
        const float* __restrict__ d0b, const float* __restrict__ d1b,
        const float* __restrict__ N0b,
        float fx, float fy, float cx, float cy, float ifx, float ify,
        float R00, float R01, float R02, float t0,
        float R10, float R11, float R12, float t1,
        float R20, float R21, float R22, float t2,
        int bx, int tid, float* __restrict__ a) {
    const int band = bx & 7;
    const int seg  = bx >> 3;
    const int pbase = band * 6144;

#pragma unroll 2
    for (int item = 0; item < 6; ++item) {
        const int gl = item*8192 + seg*256 + tid;
        const int c = gl / 6144;
        const int pl = gl - c*6144;
        const int p = pbase + pl;
        const int h = p >> 8;
        const int w = p & 255;
        const float d1v = d1b[p];
        const float d0v = d0b[p];
        const float pxv = ((float)w - cx)*ifx;
        const float pyv = ((float)h - cy)*ify;
        const float V1x = pxv*d1v, V1y = pyv*d1v, V1z = d1v;
        const float X = R00*V1x + R01*V1y + R02*V1z + t0;
        const float Y = R10*V1x + R11*V1y + R12*V1z + t1;
        const float Z = R20*V1x + R21*V1y + R22*V1z + t2;

        bool valid = (Z > 1e-8f) && (d0v > 0.f) && (d1v > 0.f);
        float u = 0.f, v = 0.f, invz = 1.f;
        if (valid) {
            invz = 1.0f / Z;
            u = fx*X*invz + cx;
            v = fy*Y*invz + cy;
            valid = (u > 0.f && u < (float)(W_-1) && v > 0.f && v < (float)(H_-1));
        }
        if (!valid) continue;

        const float u0f = floorf(u), v0f = floorf(v);
        const int u0 = (int)u0f, v0 = (int)v0f;
        const float du = u - u0f, dv = v - v0f;
        const float w00 = (1.f-du)*(1.f-dv), w10 = du*(1.f-dv);
        const float w01 = (1.f-du)*dv,       w11 = du*dv;
        const int i00 = v0*W_ + u0, i01 = i00 + W_;

        const float Jp00 = fx*invz, Jp02 = -fx*X*invz*invz;
        const float Jp11 = fy*invz, Jp12 = -fy*Y*invz*invz;
        float Jw0[6], Jw1[6];
        {
            const float Jt_[3][6] = {
                {0.f,  Z, -Y, 1.f, 0.f, 0.f},
                {-Z, 0.f,  X, 0.f, 1.f, 0.f},
                { Y,  -X, 0.f, 0.f, 0.f, 1.f}};
#pragma unroll
            for (int k = 0; k < 6; k++) {
                Jw0[k] = Jp00*Jt_[0][k] + Jp02*Jt_[2][k];
                Jw1[k] = Jp11*Jt_[1][k] + Jp12*Jt_[2][k];
            }
        }

        // ---- photometric channel c ----
        {
            const float* Ic = I0b + c*HW_;
            const int r0 = v0*W_, r1 = r0 + W_;
            const int rm = max(v0-1,0)*W_, rp = min(v0+2,H_-1)*W_;
            float fm0,f00,f10,fp0, fm1,f01,f11,fp1, g0a,g0b,g1a,g1b;
            if (u0 >= 1 && u0 <= W_-3) {
                const f4a A0 = *(const f4a*)(Ic + r0 + u0 - 1);
                const f4a A1 = *(const f4a*)(Ic + r1 + u0 - 1);
                const f2a Bm = *(const f2a*)(Ic + rm + u0);
                const f2a Bp = *(const f2a*)(Ic + rp + u0);
                fm0=A0.x; f00=A0.y; f10=A0.z; fp0=A0.w;
                fm1=A1.x; f01=A1.y; f11=A1.z; fp1=A1.w;
                g0a=Bm.x; g0b=Bm.y; g1a=Bp.x; g1b=Bp.y;
            } else {
                const int um = max(u0-1, 0), up = min(u0+2, W_-1);
                f00=Ic[r0+u0]; f10=Ic[r0+u0+1]; f01=Ic[r1+u0]; f11=Ic[r1+u0+1];
                fm0=Ic[r0+um]; fp0=Ic[r0+up];   fm1=Ic[r1+um]; fp1=Ic[r1+up];
                g0a=Ic[rm+u0]; g0b=Ic[rm+u0+1]; g1a=Ic[rp+u0]; g1b=Ic[rp+u0+1];
            }
            const float I0w = w00*f00 + w10*f10 + w01*f01 + w11*f11;
            const float gx00 = 0.5f*(f10 - fm0);
            const float gx10 = 0.5f*(fp0 - f00);
            const float gx01 = 0.5f*(f11 - fm1);
            const float gx11 = 0.5f*(fp1 - f01);
            const float gy00 = 0.5f*(f01 - g0a);
            const float gy10 = 0.5f*(f11 - g0b);
            const float gy01 = 0.5f*(g1a - f00);
            const float gy11 = 0.5f*(g1b - f10);
            const float gx = w00*gx00 + w10*gx10 + w01*gx01 + w11*gx11;
            const float gy = w00*gy00 + w10*gy10 + w01*gy01 + w11*gy11;
            const float rv = I1b[c*HW_ + p] - I0w;
            float Jr[6];
#pragma unroll
            for (int k = 0; k < 6; k++) Jr[k] = gx*Jw0[k] + gy*Jw1[k];
            const float ar = fabsf(rv);
            const float wt = (ar <= HUBER) ? 1.f : HUBER / fmaxf(ar, 1e-12f);
            int cnt = 0;
#pragma unroll
            for (int i2 = 0; i2 < 6; i2++) {
                const float wJ = wt * Jr[i2];
#pragma unroll
                for (int j2 = i2; j2 < 6; j2++) a[cnt++] += wJ * Jr[j2];
                a[21+i2] += wJ * rv;
            }
        }

        // ---- ICP channel (c==0 items only) ----
        if (c == 0) {
            const f2a D0 = *(const f2a*)(d0b + i00);
            const f2a D1 = *(const f2a*)(d0b + i01);
            const float dc00 = D0.x, dc10 = D0.y, dc01 = D1.x, dc11 = D1.y;
            const float pxu0 = ((float)u0 - cx)*ifx, pxu1 = ((float)(u0+1) - cx)*ifx;
            const float pyv0 = ((float)v0 - cy)*ify, pyv1 = ((float)(v0+1) - cy)*ify;
            const float rVx = w00*pxu0*dc00 + w10*pxu1*dc10 + w01*pxu0*dc01 + w11*pxu1*dc11;
            const float rVy = w00*pyv0*dc00 + w10*pyv0*dc10 + w01*pyv1*dc01 + w11*pyv1*dc11;
            const float rVz = w00*dc00 + w10*dc10 + w01*dc01 + w11*dc11;
            float rN[3];
#pragma unroll
            for (int cc = 0; cc < 3; cc++) {
                const float* Nc = N0b + cc*HW_;
                const f2a Na = *(const f2a*)(Nc + i00);
                const f2a Nb = *(const f2a*)(Nc + i01);
                rN[cc] = w00*Na.x + w10*Na.y + w01*Nb.x + w11*Nb.y;
            }
            const float dfx = X - rVx, dfy = Y - rVy, dfz = Z - rVz;
            const float dn = sqrtf(dfx*dfx + dfy*dfy + dfz*dfz + 1e-12f);
            const bool occ = dn > 0.1f;
            const float res = rN[0]*dfx + rN[1]*dfy + rN[2]*dfz;
            const float NtC0 = rN[0]*R00 + rN[1]*R10 + rN[2]*R20;
            const float NtC1 = rN[0]*R01 + rN[1]*R11 + rN[2]*R21;
            const float NtC2 = rN[0]*R02 + rN[1]*R12 + rN[2]*R22;
            const float Jr0 = NtC1*V1z - NtC2*V1y;
            const float Jr1 = NtC2*V1x - NtC0*V1z;
            const float Jr2 = NtC0*V1y - NtC1*V1x;
            const float sd0 = d1v * (5.5f/525.0f);
            const float sd2 = d1v * d1v * (0.4f/(525.0f*1.2f));
            const float cov = (NtC0*NtC0 + NtC1*NtC1)*sd0*sd0 + NtC2*NtC2*sd2*sd2;
            const float sigma = sqrtf(cov + 1e-8f);
            const float invs = 1.0f/(sigma + 1e-8f);
            const float rZ = occ ? 1e-6f : res*invs;
            float Jr[6];
            Jr[0] = GEOMW * (-Jr0*invs);
            Jr[1] = GEOMW * (-Jr1*invs);
            Jr[2] = GEOMW * (-Jr2*invs);
            Jr[3] = GEOMW * ( NtC0*invs);
            Jr[4] = GEOMW * ( NtC1*invs);
            Jr[5] = GEOMW * ( NtC2*invs);
            const float rv = -GEOMW * rZ;
            const float ar = fabsf(rv);
            const float wt = (ar <= HUBER) ? 1.f : HUBER / fmaxf(ar, 1e-12f);
            int cnt = 0;
#pragma unroll
            for (int i2 = 0; i2 < 6; i2++) {
                const float wJ = wt * Jr[i2];
#pragma unroll
                for (int j2 = i2; j2 < 6; j2++) a[cnt++] += wJ * Jr[j2];
                a[21+i2] += wJ * rv;
            }
        }
    }
}

// solve for batch b; Msh is per-batch LDS scratch (keeps VGPR off hot path)
__device__ void solve_b(float* __restrict__ accb, float (*Msh)[7],
                        float* __restrict__ poseb, float* __restrict__ outb) {
    float av[27];
#pragma unroll
    for (int k = 0; k < 27; k++) av[k] = atomicAdd(&accb[k], 0.0f);  // coherent read
    {
        int cnt = 0;
        for (int i = 0; i < 6; i++)
            for (int j = i; j < 6; j++) { Msh[i][j] = av[cnt]; Msh[j][i] = av[cnt]; cnt++; }
        for (int i = 0; i < 6; i++) {
            Msh[i][i] += LMEPS;
            Msh[i][6] = av[21+i];
        }
    }
    for (int k = 0; k < 6; k++) {
        int piv = k; float mx = fabsf(Msh[k][k]);
        for (int r = k+1; r < 6; r++) { float vv = fabsf(Msh[r][k]); if (vv > mx) { mx = vv; piv = r; } }
        if (piv != k)
            for (int j = 0; j < 7; j++) { float tmp = Msh[k][j]; Msh[k][j] = Msh[piv][j]; Msh[piv][j] = tmp; }
        const float inv = 1.0f / Msh[k][k];
        for (int r = k+1; r < 6; r++) {
            const float f = Msh[r][k] * inv;
            for (int j = k; j < 7; j++) Msh[r][j] -= f * Msh[k][j];
        }
    }
    float xi[6];
    for (int i = 5; i >= 0; i--) {
        float s = Msh[i][6];
        for (int j = i+1; j < 6; j++) s -= Msh[i][j]*xi[j];
        xi[i] = s / Msh[i][i];
    }
    const float wx = xi[0], wy = xi[1], wz = xi[2];
    const float th2 = wx*wx + wy*wy + wz*wz;
    float A, Bc, Cc;
    if (th2 < 1e-8f) {
        A  = 1.f - th2/6.f;
        Bc = 0.5f - th2/24.f;
        Cc = 1.f/6.f - th2/120.f;
    } else {
        const float th = sqrtf(th2);
        const float s = sinf(th), cth = cosf(th);
        A  = s/th;
        Bc = (1.f - cth)/th2;
        Cc = (th - s)/(th2*th);
    }
    float K[3][3] = {{0.f, -wz, wy}, {wz, 0.f, -wx}, {-wy, wx, 0.f}};
    float K2[3][3];
    for (int i = 0; i < 3; i++)
        for (int j = 0; j < 3; j++)
            K2[i][j] = K[i][0]*K[0][j] + K[i][1]*K[1][j] + K[i][2]*K[2][j];
    float Re[3][3], Vm[3][3];
    for (int i = 0; i < 3; i++)
        for (int j = 0; j < 3; j++) {
            const float eye = (i == j) ? 1.f : 0.f;
            Re[i][j] = eye + A*K[i][j] + Bc*K2[i][j];
            Vm[i][j] = eye + Bc*K[i][j] + Cc*K2[i][j];
        }
    float tt[3];
    for (int i = 0; i < 3; i++)
        tt[i] = Vm[i][0]*xi[3] + Vm[i][1]*xi[4] + Vm[i][2]*xi[5];
    float Pold[16], Pnew[16];
    for (int i = 0; i < 16; i++) Pold[i] = poseb[i];
    for (int j = 0; j < 4; j++) {
        for (int i = 0; i < 3; i++)
            Pnew[i*4+j] = Re[i][0]*Pold[0*4+j] + Re[i][1]*Pold[1*4+j] + Re[i][2]*Pold[2*4+j] + tt[i]*Pold[3*4+j];
        Pnew[3*4+j] = Pold[3*4+j];
    }
    for (int i = 0; i < 16; i++) { poseb[i] = Pnew[i]; outb[i] = Pnew[i]; }
}

// ---------- single cooperative kernel: init + 3x(accumulate + solve) ----------
// grid dim3(256, B_) = 1024 blocks = exactly 4/CU; launch_bounds(256,4) caps
// VGPR at 128 (hot path measured 48 in r8 -> no spill). Solve matrix in LDS.
__global__ __launch_bounds__(256, 4)
void fused_kernel(const float* __restrict__ I0, const float* __restrict__ I1,
                  const float* __restrict__ depth0, const float* __restrict__ depth1,
                  const float* __restrict__ intr, const float* __restrict__ pose0,
                  float* __restrict__ N0, float* __restrict__ acc,
                  float* __restrict__ poseb_all, float* __restrict__ out) {
    cg::grid_group grid = cg::this_grid();
    const int tid = (int)threadIdx.x;
    const int bx = (int)blockIdx.x;
    const int b = (int)blockIdx.y;
    const int gtid = (b * 256 + bx) * 256 + tid;

    // ---- phase 0: init ----
    if (gtid < ACC_SZ) acc[gtid] = 0.f;
    if (gtid < POSE_SZ) poseb_all[gtid] = pose0[gtid];
    if (gtid < B_*HW_) {
        const int bb = gtid / HW_;
        const int p = gtid - bb*HW_;
        float nx, ny, nz;
        compute_normal(depth0 + bb*HW_, intr[bb*4+0], intr[bb*4+1], intr[bb*4+2], intr[bb*4+3],
                       p, &nx, &ny, &nz);
        N0[(bb*3+0)*HW_ + p] = nx;
        N0[(bb*3+1)*HW_ + p] = ny;
        N0[(bb*3+2)*HW_ + p] = nz;
    }
    grid.sync();

    const float fx = intr[b*4+0], fy = intr[b*4+1], cx = intr[b*4+2], cy = intr[b*4+3];
    const float ifx = 1.0f/fx, ify = 1.0f/fy;
    const float* I0b = I0 + b*C_*HW_;
    const float* I1b = I1 + b*C_*HW_;
    const float* d0b = depth0 + b*HW_;
    const float* d1b = depth1 + b*HW_;
    const float* N0b = N0 + b*3*HW_;
    float* poseb = poseb_all + b*16;

    __shared__ float red[4][27];
    __shared__ float Msh[4][6][7];

    for (int it = 0; it < 3; ++it) {
        const float R00 = poseb[0],  R01 = poseb[1],  R02 = poseb[2],  t0 = poseb[3];
        const float R10 = poseb[4],  R11 = poseb[5],  R12 = poseb[6],  t1 = poseb[7];
        const float R20 = poseb[8],  R21 = poseb[9],  R22 = poseb[10], t2 = poseb[11];

        float a[27];
#pragma unroll
        for (int i = 0; i < 27; i++) a[i] = 0.f;

        accum_items(I0b, I1b, d0b, d1b, N0b, fx, fy, cx, cy, ifx, ify,
                    R00, R01, R02, t0, R10, R11, R12, t1, R20, R21, R22, t2,
                    bx, tid, a);

        // reduction: wave shuffle -> LDS per wave -> 27 atomics per block
        float* accb = acc + it*B_*32 + b*32;
        const int wid  = tid >> 6;
        const int lane = tid & 63;
#pragma unroll
        for (int k = 0; k < 27; k++) {
            float val = a[k];
            for (int off = 32; off > 0; off >>= 1)
                val += __shfl_down(val, off, 64);
            if (lane == 0) red[wid][k] = val;
        }
        __syncthreads();
        if (tid < 27) {
            const int k = tid;
            atomicAdd(&accb[k], red[0][k] + red[1][k] + red[2][k] + red[3][k]);
        }

        grid.sync();
        if (bx == 0 && b == 0 && tid < B_) {
            solve_b(acc + it*B_*32 + tid*32, Msh[tid],
                    poseb_all + tid*16, out + tid*16);
            __threadfence();
        }
        grid.sync();
    }
}

// ---------- fallback path (r8): plain kernels ----------

__global__ void precompute_kernel(const float* __restrict__ depth0,
                                  const float* __restrict__ intr,
                                  const float* __restrict__ pose0,
                                  float* __restrict__ N0,
                                  float* __restrict__ acc,
                                  float* __restrict__ poseb) {
    int idx = blockIdx.x * blockDim.x + threadIdx.x;
    if (idx < ACC_SZ) acc[idx] = 0.f;
    if (idx < POSE_SZ) poseb[idx] = pose0[idx];
    if (idx >= B_ * HW_) return;
    int b = idx / HW_;
    int p = idx - b * HW_;
    float nx, ny, nz;
    compute_normal(depth0 + b*HW_, intr[b*4+0], intr[b*4+1], intr[b*4+2], intr[b*4+3],
                   p, &nx, &ny, &nz);
    N0[(b*3+0)*HW_ + p] = nx;
    N0[(b*3+1)*HW_ + p] = ny;
    N0[(b*3+2)*HW_ + p] = nz;
}

__global__ __launch_bounds__(256)
void accumulate_kernel(const float* __restrict__ I0,
                       const float* __restrict__ I1,
                       const float* __restrict__ depth0,
                       const float* __restrict__ depth1,
                       const float* __restrict__ intr,
                       const float* __restrict__ N0,
                       const float* __restrict__ poseb,
                       float* __restrict__ acc) {
    const int b = blockIdx.y;
    const float* P = poseb + b*16;
    const float fx = intr[b*4+0], fy = intr[b*4+1], cx = intr[b*4+2], cy = intr[b*4+3];
    const float ifx = 1.0f/fx, ify = 1.0f/fy;
    float a[27];
#pragma unroll
    for (int i = 0; i < 27; i++) a[i] = 0.f;
    accum_items(I0 + b*C_*HW_, I1 + b*C_*HW_, depth0 + b*HW_, depth1 + b*HW_,
                N0 + b*3*HW_, fx, fy, cx, cy, ifx, ify,
                P[0], P[1], P[2], P[3], P[4], P[5], P[6], P[7], P[8], P[9], P[10], P[11],
                (int)blockIdx.x, (int)threadIdx.x, a);
    __shared__ float red[4][27];
    const int wid  = threadIdx.x >> 6;
    const int lane = threadIdx.x & 63;
#pragma unroll
    for (int k = 0; k < 27; k++) {
        float val = a[k];
        for (int off = 32; off > 0; off >>= 1)
            val += __shfl_down(val, off, 64);
        if (lane == 0) red[wid][k] = val;
    }
    __syncthreads();
    if (threadIdx.x < 27) {
        const int k = threadIdx.x;
        atomicAdd(&acc[b*32 + k], red[0][k] + red[1][k] + red[2][k] + red[3][k]);
    }
}

__global__ void solve_kernel(float* __restrict__ acc,
                             float* __restrict__ poseb,
                             float* __restrict__ out) {
    __shared__ float Msh[4][6][7];
    int b = threadIdx.x;
    if (b >= B_) return;
    solve_b(acc + b*32, Msh[b], poseb + b*16, out + b*16);
}

extern "C" void kernel_launch(void* const* d_in, const int* in_sizes, int n_in,
                              void* d_out, int out_size, void* d_ws, size_t ws_size,
                              hipStream_t stream) {
    const float* pose0  = (const float*)d_in[0];
    const float* I0     = (const float*)d_in[1];
    const float* I1     = (const float*)d_in[2];
    const float* intr   = (const float*)d_in[5];
    const float* depth0 = (const float*)d_in[6];
    const float* depth1 = (const float*)d_in[7];
    float* ws    = (float*)d_ws;
    float* N0    = ws;
    float* acc   = ws + N0_SZ;
    float* poseb = acc + ACC_SZ;
    float* out   = (float*)d_out;

    void* args[] = { (void*)&I0, (void*)&I1, (void*)&depth0, (void*)&depth1,
                     (void*)&intr, (void*)&pose0, (void*)&N0, (void*)&acc,
                     (void*)&poseb, (void*)&out };
    hipError_t e = hipLaunchCooperativeKernel((const void*)fused_kernel,
                                              dim3(256, B_), dim3(256), args, 0, stream);
    if (e != hipSuccess) {
        // deterministic fallback: proven r8 multi-dispatch path
        precompute_kernel<<<(B_*HW_ + 255)/256, 256, 0, stream>>>(depth0, intr, pose0, N0, acc, poseb);
        for (int it = 0; it < 3; it++) {
            accumulate_kernel<<<dim3(256, B_), 256, 0, stream>>>(
                I0, I1, depth0, depth1, intr, N0, poseb, acc + it*B_*32);
            solve_kernel<<<1, 64, 0, stream>>>(acc + it*B_*32, poseb, out);
        }
    }
}

// Round 11
// 206.703 us; speedup vs baseline: 3.8445x; 3.8445x over previous
//
#include <hip/hip_runtime.h>
#include <math.h>

#define B_ 4
#define C_ 8
#define H_ 192
#define W_ 256
#define HW_ (H_*W_)
#define GEOMW 0.01f
#define HUBER 0.5f
#define LMEPS 1e-6f

// ws layout (floats)
#define N0_SZ  (B_*3*HW_)
#define ACC_SZ (3*B_*32)
#define CNT_SZ 16
#define POSE_SZ (B_*16)

typedef float f4a __attribute__((ext_vector_type(4), aligned(4)));
typedef float f2a __attribute__((ext_vector_type(2), aligned(4)));

// precompute normals + zero acc/cnt + copy pose0 -> poseb
__global__ void precompute_kernel(const float* __restrict__ depth0,
                                  const float* __restrict__ intr,
                                  const float* __restrict__ pose0,
                                  float* __restrict__ N0,
                                  float* __restrict__ acc,
                                  unsigned int* __restrict__ cnt,
                                  float* __restrict__ poseb) {
    int idx = blockIdx.x * blockDim.x + threadIdx.x;
    if (idx < ACC_SZ) acc[idx] = 0.f;
    if (idx < CNT_SZ) cnt[idx] = 0u;
    if (idx < POSE_SZ) poseb[idx] = pose0[idx];
    if (idx >= B_ * HW_) return;
    int b = idx / HW_;
    int p = idx - b * HW_;
    int h = p >> 8;
    int w = p & 255;
    float fx = intr[b*4+0], fy = intr[b*4+1], cx = intr[b*4+2], cy = intr[b*4+3];
    const float* d = depth0 + b * HW_;
    int wl = max(w-1, 0), wr = min(w+1, W_-1);
    int hu = max(h-1, 0), hd = min(h+1, H_-1);
    float dr = d[h*W_ + wr], dl = d[h*W_ + wl];
    float dd = d[hd*W_ + w], du_ = d[hu*W_ + w];
    float pxr = ((float)wr - cx)/fx, pxl = ((float)wl - cx)/fx;
    float pyh = ((float)h  - cy)/fy;
    float pxw = ((float)w  - cx)/fx;
    float pyd = ((float)hd - cy)/fy, pyu = ((float)hu - cy)/fy;
    float dxx = 0.5f*(pxr*dr - pxl*dl), dxy = 0.5f*(pyh*dr - pyh*dl), dxz = 0.5f*(dr - dl);
    float dyx = 0.5f*(pxw*dd - pxw*du_), dyy = 0.5f*(pyd*dd - pyu*du_), dyz = 0.5f*(dd - du_);
    float n0 = dxy*dyz - dxz*dyy;
    float n1 = dxz*dyx - dxx*dyz;
    float n2 = dxx*dyy - dxy*dyx;
    float inv = 1.0f / sqrtf(n0*n0 + n1*n1 + n2*n2 + 1e-12f);
    N0[(b*3+0)*HW_ + p] = n0*inv;
    N0[(b*3+1)*HW_ + p] = n1*inv;
    N0[(b*3+2)*HW_ + p] = n2*inv;
}

// 6x6 LM solve + SE3 exp + pose update; M in LDS to keep VGPRs low.
__device__ void solve_b(float* __restrict__ accb, float (*Msh)[7],
                        float* __restrict__ poseb, float* __restrict__ outb) {
    float av[27];
#pragma unroll
    for (int k = 0; k < 27; k++) av[k] = atomicAdd(&accb[k], 0.0f);  // coherent read
    {
        int cnt = 0;
        for (int i = 0; i < 6; i++)
            for (int j = i; j < 6; j++) { Msh[i][j] = av[cnt]; Msh[j][i] = av[cnt]; cnt++; }
        for (int i = 0; i < 6; i++) {
            Msh[i][i] += LMEPS;
            Msh[i][6] = av[21+i];
        }
    }
    for (int k = 0; k < 6; k++) {
        int piv = k; float mx = fabsf(Msh[k][k]);
        for (int r = k+1; r < 6; r++) { float vv = fabsf(Msh[r][k]); if (vv > mx) { mx = vv; piv = r; } }
        if (piv != k)
            for (int j = 0; j < 7; j++) { float tmp = Msh[k][j]; Msh[k][j] = Msh[piv][j]; Msh[piv][j] = tmp; }
        const float inv = 1.0f / Msh[k][k];
        for (int r = k+1; r < 6; r++) {
            const float f = Msh[r][k] * inv;
            for (int j = k; j < 7; j++) Msh[r][j] -= f * Msh[k][j];
        }
    }
    float xi[6];
    for (int i = 5; i >= 0; i--) {
        float s = Msh[i][6];
        for (int j = i+1; j < 6; j++) s -= Msh[i][j]*xi[j];
        xi[i] = s / Msh[i][i];
    }
    const float wx = xi[0], wy = xi[1], wz = xi[2];
    const float th2 = wx*wx + wy*wy + wz*wz;
    float A, Bc, Cc;
    if (th2 < 1e-8f) {
        A  = 1.f - th2/6.f;
        Bc = 0.5f - th2/24.f;
        Cc = 1.f/6.f - th2/120.f;
    } else {
        const float th = sqrtf(th2);
        const float s = sinf(th), cth = cosf(th);
        A  = s/th;
        Bc = (1.f - cth)/th2;
        Cc = (th - s)/(th2*th);
    }
    float K[3][3] = {{0.f, -wz, wy}, {wz, 0.f, -wx}, {-wy, wx, 0.f}};
    float K2[3][3];
    for (int i = 0; i < 3; i++)
        for (int j = 0; j < 3; j++)
            K2[i][j] = K[i][0]*K[0][j] + K[i][1]*K[1][j] + K[i][2]*K[2][j];
    float Re[3][3], Vm[3][3];
    for (int i = 0; i < 3; i++)
        for (int j = 0; j < 3; j++) {
            const float eye = (i == j) ? 1.f : 0.f;
            Re[i][j] = eye + A*K[i][j] + Bc*K2[i][j];
            Vm[i][j] = eye + Bc*K[i][j] + Cc*K2[i][j];
        }
    float tt[3];
    for (int i = 0; i < 3; i++)
        tt[i] = Vm[i][0]*xi[3] + Vm[i][1]*xi[4] + Vm[i][2]*xi[5];
    float Pold[16], Pnew[16];
    for (int i = 0; i < 16; i++) Pold[i] = poseb[i];
    for (int j = 0; j < 4; j++) {
        for (int i = 0; i < 3; i++)
            Pnew[i*4+j] = Re[i][0]*Pold[0*4+j] + Re[i][1]*Pold[1*4+j] + Re[i][2]*Pold[2*4+j] + tt[i]*Pold[3*4+j];
        Pnew[3*4+j] = Pold[3*4+j];
    }
    for (int i = 0; i < 16; i++) { poseb[i] = Pnew[i]; outb[i] = Pnew[i]; }
}

// r8 hot loop verbatim (6 items/thread, band swizzle) + last-block-done solve.
// Every block reads poseb in its prologue; the last block per batch runs solve
// only after all 1024 blocks incremented cnt -> no read-after-write hazard.
__global__ __launch_bounds__(256)
void accumulate_kernel(const float* __restrict__ I0,
                       const float* __restrict__ I1,
                       const float* __restrict__ depth0,
                       const float* __restrict__ depth1,
                       const float* __restrict__ intr,
                       const float* __restrict__ N0,
                       float* __restrict__ poseb_all,
                       float* __restrict__ acc,        // this iter's acc (B_*32)
                       unsigned int* __restrict__ cnt, // this iter's counters (B_)
                       float* __restrict__ out) {
    const int b = blockIdx.y;
    float* poseb = poseb_all + b*16;
    const float R00 = poseb[0],  R01 = poseb[1],  R02 = poseb[2],  t0 = poseb[3];
    const float R10 = poseb[4],  R11 = poseb[5],  R12 = poseb[6],  t1 = poseb[7];
    const float R20 = poseb[8],  R21 = poseb[9],  R22 = poseb[10], t2 = poseb[11];
    const float fx = intr[b*4+0], fy = intr[b*4+1], cx = intr[b*4+2], cy = intr[b*4+3];
    const float ifx = 1.0f/fx, ify = 1.0f/fy;
    const float* I0b = I0 + b*C_*HW_;
    const float* I1b = I1 + b*C_*HW_;
    const float* d0b = depth0 + b*HW_;
    const float* d1b = depth1 + b*HW_;
    const float* N0b = N0 + b*3*HW_;
    float* accb = acc + b*32;

    const int band = (int)blockIdx.x & 7;       // -> XCD via round-robin dispatch
    const int seg  = (int)blockIdx.x >> 3;      // 32 segments per band
    const int pbase = band * 6144;              // 24 rows * 256 px

    float a[27];
#pragma unroll
    for (int i = 0; i < 27; i++) a[i] = 0.f;

#pragma unroll 2
    for (int item = 0; item < 6; ++item) {
        const int gl = item*8192 + seg*256 + (int)threadIdx.x;
        const int c = gl / 6144;
        const int pl = gl - c*6144;
        const int p = pbase + pl;
        const int h = p >> 8;         // W_ = 256
        const int w = p & 255;
        const float d1v = d1b[p];
        const float d0v = d0b[p];
        const float pxv = ((float)w - cx)*ifx;
        const float pyv = ((float)h - cy)*ify;
        const float V1x = pxv*d1v, V1y = pyv*d1v, V1z = d1v;
        const float X = R00*V1x + R01*V1y + R02*V1z + t0;
        const float Y = R10*V1x + R11*V1y + R12*V1z + t1;
        const float Z = R20*V1x + R21*V1y + R22*V1z + t2;

        bool valid = (Z > 1e-8f) && (d0v > 0.f) && (d1v > 0.f);
        float u = 0.f, v = 0.f, invz = 1.f;
        if (valid) {
            invz = 1.0f / Z;
            u = fx*X*invz + cx;
            v = fy*Y*invz + cy;
            valid = (u > 0.f && u < (float)(W_-1) && v > 0.f && v < (float)(H_-1));
        }
        if (!valid) continue;

        const float u0f = floorf(u), v0f = floorf(v);
        const int u0 = (int)u0f, v0 = (int)v0f;
        const float du = u - u0f, dv = v - v0f;
        const float w00 = (1.f-du)*(1.f-dv), w10 = du*(1.f-dv);
        const float w01 = (1.f-du)*dv,       w11 = du*dv;
        const int i00 = v0*W_ + u0, i01 = i00 + W_;

        const float Jp00 = fx*invz, Jp02 = -fx*X*invz*invz;
        const float Jp11 = fy*invz, Jp12 = -fy*Y*invz*invz;
        float Jw0[6], Jw1[6];
        {
            const float Jt_[3][6] = {
                {0.f,  Z, -Y, 1.f, 0.f, 0.f},
                {-Z, 0.f,  X, 0.f, 1.f, 0.f},
                { Y,  -X, 0.f, 0.f, 0.f, 1.f}};
#pragma unroll
            for (int k = 0; k < 6; k++) {
                Jw0[k] = Jp00*Jt_[0][k] + Jp02*Jt_[2][k];
                Jw1[k] = Jp11*Jt_[1][k] + Jp12*Jt_[2][k];
            }
        }

        // ---- photometric channel c ----
        {
            const float* Ic = I0b + c*HW_;
            const int r0 = v0*W_, r1 = r0 + W_;
            const int rm = max(v0-1,0)*W_, rp = min(v0+2,H_-1)*W_;
            float fm0,f00,f10,fp0, fm1,f01,f11,fp1, g0a,g0b,g1a,g1b;
            if (u0 >= 1 && u0 <= W_-3) {
                const f4a A0 = *(const f4a*)(Ic + r0 + u0 - 1);
                const f4a A1 = *(const f4a*)(Ic + r1 + u0 - 1);
                const f2a Bm = *(const f2a*)(Ic + rm + u0);
                const f2a Bp = *(const f2a*)(Ic + rp + u0);
                fm0=A0.x; f00=A0.y; f10=A0.z; fp0=A0.w;
                fm1=A1.x; f01=A1.y; f11=A1.z; fp1=A1.w;
                g0a=Bm.x; g0b=Bm.y; g1a=Bp.x; g1b=Bp.y;
            } else {
                const int um = max(u0-1, 0), up = min(u0+2, W_-1);
                f00=Ic[r0+u0]; f10=Ic[r0+u0+1]; f01=Ic[r1+u0]; f11=Ic[r1+u0+1];
                fm0=Ic[r0+um]; fp0=Ic[r0+up];   fm1=Ic[r1+um]; fp1=Ic[r1+up];
                g0a=Ic[rm+u0]; g0b=Ic[rm+u0+1]; g1a=Ic[rp+u0]; g1b=Ic[rp+u0+1];
            }
            const float I0w = w00*f00 + w10*f10 + w01*f01 + w11*f11;
            const float gx00 = 0.5f*(f10 - fm0);
            const float gx10 = 0.5f*(fp0 - f00);
            const float gx01 = 0.5f*(f11 - fm1);
            const float gx11 = 0.5f*(fp1 - f01);
            const float gy00 = 0.5f*(f01 - g0a);
            const float gy10 = 0.5f*(f11 - g0b);
            const float gy01 = 0.5f*(g1a - f00);
            const float gy11 = 0.5f*(g1b - f10);
            const float gx = w00*gx00 + w10*gx10 + w01*gx01 + w11*gx11;
            const float gy = w00*gy00 + w10*gy10 + w01*gy01 + w11*gy11;
            const float rv = I1b[c*HW_ + p] - I0w;
            float Jr[6];
#pragma unroll
            for (int k = 0; k < 6; k++) Jr[k] = gx*Jw0[k] + gy*Jw1[k];
            const float ar = fabsf(rv);
            const float wt = (ar <= HUBER) ? 1.f : HUBER / fmaxf(ar, 1e-12f);
            int cntk = 0;
#pragma unroll
            for (int i2 = 0; i2 < 6; i2++) {
                const float wJ = wt * Jr[i2];
#pragma unroll
                for (int j2 = i2; j2 < 6; j2++) a[cntk++] += wJ * Jr[j2];
                a[21+i2] += wJ * rv;
            }
        }

        // ---- ICP channel (c==0 items only) ----
        if (c == 0) {
            const f2a D0 = *(const f2a*)(d0b + i00);
            const f2a D1 = *(const f2a*)(d0b + i01);
            const float dc00 = D0.x, dc10 = D0.y, dc01 = D1.x, dc11 = D1.y;
            const float pxu0 = ((float)u0 - cx)*ifx, pxu1 = ((float)(u0+1) - cx)*ifx;
            const float pyv0 = ((float)v0 - cy)*ify, pyv1 = ((float)(v0+1) - cy)*ify;
            const float rVx = w00*pxu0*dc00 + w10*pxu1*dc10 + w01*pxu0*dc01 + w11*pxu1*dc11;
            const float rVy = w00*pyv0*dc00 + w10*pyv0*dc10 + w01*pyv1*dc01 + w11*pyv1*dc11;
            const float rVz = w00*dc00 + w10*dc10 + w01*dc01 + w11*dc11;
            float rN[3];
#pragma unroll
            for (int cc = 0; cc < 3; cc++) {
                const float* Nc = N0b + cc*HW_;
                const f2a Na = *(const f2a*)(Nc + i00);
                const f2a Nb = *(const f2a*)(Nc + i01);
                rN[cc] = w00*Na.x + w10*Na.y + w01*Nb.x + w11*Nb.y;
            }
            const float dfx = X - rVx, dfy = Y - rVy, dfz = Z - rVz;
            const float dn = sqrtf(dfx*dfx + dfy*dfy + dfz*dfz + 1e-12f);
            const bool occ = dn > 0.1f;
            const float res = rN[0]*dfx + rN[1]*dfy + rN[2]*dfz;
            const float NtC0 = rN[0]*R00 + rN[1]*R10 + rN[2]*R20;
            const float NtC1 = rN[0]*R01 + rN[1]*R11 + rN[2]*R21;
            const float NtC2 = rN[0]*R02 + rN[1]*R12 + rN[2]*R22;
            const float Jr0 = NtC1*V1z - NtC2*V1y;
            const float Jr1 = NtC2*V1x - NtC0*V1z;
            const float Jr2 = NtC0*V1y - NtC1*V1x;
            const float sd0 = d1v * (5.5f/525.0f);
            const float sd2 = d1v * d1v * (0.4f/(525.0f*1.2f));
            const float cov = (NtC0*NtC0 + NtC1*NtC1)*sd0*sd0 + NtC2*NtC2*sd2*sd2;
            const float sigma = sqrtf(cov + 1e-8f);
            const float invs = 1.0f/(sigma + 1e-8f);
            const float rZ = occ ? 1e-6f : res*invs;
            float Jr[6];
            Jr[0] = GEOMW * (-Jr0*invs);
            Jr[1] = GEOMW * (-Jr1*invs);
            Jr[2] = GEOMW * (-Jr2*invs);
            Jr[3] = GEOMW * ( NtC0*invs);
            Jr[4] = GEOMW * ( NtC1*invs);
            Jr[5] = GEOMW * ( NtC2*invs);
            const float rv = -GEOMW * rZ;
            const float ar = fabsf(rv);
            const float wt = (ar <= HUBER) ? 1.f : HUBER / fmaxf(ar, 1e-12f);
            int cntk = 0;
#pragma unroll
            for (int i2 = 0; i2 < 6; i2++) {
                const float wJ = wt * Jr[i2];
#pragma unroll
                for (int j2 = i2; j2 < 6; j2++) a[cntk++] += wJ * Jr[j2];
                a[21+i2] += wJ * rv;
            }
        }
    }

    // reduction: wave shuffle -> LDS per wave -> 27 atomics per block
    __shared__ float red[4][27];
    __shared__ float Msh[6][7];
    __shared__ unsigned s_last;
    const int wid  = threadIdx.x >> 6;
    const int lane = threadIdx.x & 63;
#pragma unroll
    for (int k = 0; k < 27; k++) {
        float val = a[k];
        for (int off = 32; off > 0; off >>= 1)
            val += __shfl_down(val, off, 64);
        if (lane == 0) red[wid][k] = val;
    }
    __syncthreads();
    if (threadIdx.x < 27) {
        const int k = threadIdx.x;
        atomicAdd(&accb[k], red[0][k] + red[1][k] + red[2][k] + red[3][k]);
    }
    __syncthreads();
    if (threadIdx.x == 0) {
        __threadfence();                        // make this block's atomics visible
        const unsigned old = atomicAdd(&cnt[b], 1u);
        s_last = (old == (unsigned)(gridDim.x - 1)) ? 1u : 0u;
    }
    __syncthreads();
    if (s_last && threadIdx.x == 0) {
        solve_b(accb, Msh, poseb, out + b*16);  // pose for next iter + output
    }
}

extern "C" void kernel_launch(void* const* d_in, const int* in_sizes, int n_in,
                              void* d_out, int out_size, void* d_ws, size_t ws_size,
                              hipStream_t stream) {
    const float* pose0  = (const float*)d_in[0];
    const float* I0     = (const float*)d_in[1];
    const float* I1     = (const float*)d_in[2];
    const float* intr   = (const float*)d_in[5];
    const float* depth0 = (const float*)d_in[6];
    const float* depth1 = (const float*)d_in[7];
    float* ws    = (float*)d_ws;
    float* N0    = ws;
    float* acc   = ws + N0_SZ;
    unsigned int* cnt = (unsigned int*)(acc + ACC_SZ);
    float* poseb = (float*)(cnt + CNT_SZ);
    float* out   = (float*)d_out;

    precompute_kernel<<<(B_*HW_ + 255)/256, 256, 0, stream>>>(
        depth0, intr, pose0, N0, acc, cnt, poseb);
    for (int it = 0; it < 3; it++) {
        accumulate_kernel<<<dim3(256, B_), 256, 0, stream>>>(
            I0, I1, depth0, depth1, intr, N0, poseb,
            acc + it*B_*32, cnt + it*B_, out);
    }
}

// Round 12
// 162.720 us; speedup vs baseline: 4.8836x; 1.2703x over previous
//
#include <hip/hip_runtime.h>
#include <math.h>

#define B_ 4
#define C_ 8
#define H_ 192
#define W_ 256
#define HW_ (H_*W_)
#define GEOMW 0.01f
#define HUBER 0.5f
#define LMEPS 1e-6f

// ws layout (floats)
#define N0_SZ  (B_*3*HW_)
// banded accumulator: per iter 27 entries x (4 batches x 16-float line),
// band b writes slot [k*64 + batch*16 + band] -> 32 contenders per address,
// each (k,batch) on its own 64B line (was: 27 floats in 2 lines, 256/addr).
#define ACC_IT (27*64)
#define ACC_SZ (3*ACC_IT)
#define POSE_SZ (B_*16)

// 4-byte-aligned vector types (bilinear taps are only 4B aligned)
typedef float f4a __attribute__((ext_vector_type(4), aligned(4)));
typedef float f2a __attribute__((ext_vector_type(2), aligned(4)));

// precompute normals + zero acc + copy pose0 -> poseb (all init in one dispatch)
__global__ void precompute_kernel(const float* __restrict__ depth0,
                                  const float* __restrict__ intr,
                                  const float* __restrict__ pose0,
                                  float* __restrict__ N0,
                                  float* __restrict__ acc,
                                  float* __restrict__ poseb) {
    int idx = blockIdx.x * blockDim.x + threadIdx.x;
    if (idx < ACC_SZ) acc[idx] = 0.f;
    if (idx < POSE_SZ) poseb[idx] = pose0[idx];
    if (idx >= B_ * HW_) return;
    int b = idx / HW_;
    int p = idx - b * HW_;
    int h = p >> 8;
    int w = p & 255;
    float fx = intr[b*4+0], fy = intr[b*4+1], cx = intr[b*4+2], cy = intr[b*4+3];
    const float* d = depth0 + b * HW_;
    int wl = max(w-1, 0), wr = min(w+1, W_-1);
    int hu = max(h-1, 0), hd = min(h+1, H_-1);
    float dr = d[h*W_ + wr], dl = d[h*W_ + wl];
    float dd = d[hd*W_ + w], du_ = d[hu*W_ + w];
    float pxr = ((float)wr - cx)/fx, pxl = ((float)wl - cx)/fx;
    float pyh = ((float)h  - cy)/fy;
    float pxw = ((float)w  - cx)/fx;
    float pyd = ((float)hd - cy)/fy, pyu = ((float)hu - cy)/fy;
    float dxx = 0.5f*(pxr*dr - pxl*dl), dxy = 0.5f*(pyh*dr - pyh*dl), dxz = 0.5f*(dr - dl);
    float dyx = 0.5f*(pxw*dd - pxw*du_), dyy = 0.5f*(pyd*dd - pyu*du_), dyz = 0.5f*(dd - du_);
    float n0 = dxy*dyz - dxz*dyy;
    float n1 = dxz*dyx - dxx*dyz;
    float n2 = dxx*dyy - dxy*dyx;
    float inv = 1.0f / sqrtf(n0*n0 + n1*n1 + n2*n2 + 1e-12f);
    N0[(b*3+0)*HW_ + p] = n0*inv;
    N0[(b*3+1)*HW_ + p] = n1*inv;
    N0[(b*3+2)*HW_ + p] = n2*inv;
}

// r8 structure verbatim (6 items/thread, grid dim3(256,B_), band swizzle);
// only the final atomics changed to the banded layout.
__global__ __launch_bounds__(256)
void accumulate_kernel(const float* __restrict__ I0,
                       const float* __restrict__ I1,
                       const float* __restrict__ depth0,
                       const float* __restrict__ depth1,
                       const float* __restrict__ intr,
                       const float* __restrict__ N0,
                       const float* __restrict__ poseb,
                       float* __restrict__ acc) {   // this iter's ACC_IT floats
    const int b = blockIdx.y;
    const float* P = poseb + b*16;
    const float R00 = P[0],  R01 = P[1],  R02 = P[2],  t0 = P[3];
    const float R10 = P[4],  R11 = P[5],  R12 = P[6],  t1 = P[7];
    const float R20 = P[8],  R21 = P[9],  R22 = P[10], t2 = P[11];
    const float fx = intr[b*4+0], fy = intr[b*4+1], cx = intr[b*4+2], cy = intr[b*4+3];
    const float ifx = 1.0f/fx, ify = 1.0f/fy;
    const float* I0b = I0 + b*C_*HW_;
    const float* I1b = I1 + b*C_*HW_;
    const float* d0b = depth0 + b*HW_;
    const float* d1b = depth1 + b*HW_;
    const float* N0b = N0 + b*3*HW_;

    const int band = (int)blockIdx.x & 7;       // -> XCD via round-robin dispatch
    const int seg  = (int)blockIdx.x >> 3;      // 32 segments per band
    const int pbase = band * 6144;              // 24 rows * 256 px

    float a[27];
#pragma unroll
    for (int i = 0; i < 27; i++) a[i] = 0.f;

#pragma unroll 2
    for (int item = 0; item < 6; ++item) {
        // gl in [0, 49152): 8 channels x 6144 band pixels
        const int gl = item*8192 + seg*256 + (int)threadIdx.x;
        const int c = gl / 6144;
        const int pl = gl - c*6144;
        const int p = pbase + pl;
        const int h = p >> 8;         // W_ = 256
        const int w = p & 255;
        const float d1v = d1b[p];
        const float d0v = d0b[p];
        const float pxv = ((float)w - cx)*ifx;
        const float pyv = ((float)h - cy)*ify;
        const float V1x = pxv*d1v, V1y = pyv*d1v, V1z = d1v;
        const float X = R00*V1x + R01*V1y + R02*V1z + t0;
        const float Y = R10*V1x + R11*V1y + R12*V1z + t1;
        const float Z = R20*V1x + R21*V1y + R22*V1z + t2;

        bool valid = (Z > 1e-8f) && (d0v > 0.f) && (d1v > 0.f);
        float u = 0.f, v = 0.f, invz = 1.f;
        if (valid) {
            invz = 1.0f / Z;
            u = fx*X*invz + cx;
            v = fy*Y*invz + cy;
            valid = (u > 0.f && u < (float)(W_-1) && v > 0.f && v < (float)(H_-1));
        }
        if (!valid) continue;

        const float u0f = floorf(u), v0f = floorf(v);
        const int u0 = (int)u0f, v0 = (int)v0f;
        const float du = u - u0f, dv = v - v0f;
        const float w00 = (1.f-du)*(1.f-dv), w10 = du*(1.f-dv);
        const float w01 = (1.f-du)*dv,       w11 = du*dv;
        const int i00 = v0*W_ + u0, i01 = i00 + W_;

        const float Jp00 = fx*invz, Jp02 = -fx*X*invz*invz;
        const float Jp11 = fy*invz, Jp12 = -fy*Y*invz*invz;
        float Jw0[6], Jw1[6];
        {
            const float Jt_[3][6] = {
                {0.f,  Z, -Y, 1.f, 0.f, 0.f},
                {-Z, 0.f,  X, 0.f, 1.f, 0.f},
                { Y,  -X, 0.f, 0.f, 0.f, 1.f}};
#pragma unroll
            for (int k = 0; k < 6; k++) {
                Jw0[k] = Jp00*Jt_[0][k] + Jp02*Jt_[2][k];
                Jw1[k] = Jp11*Jt_[1][k] + Jp12*Jt_[2][k];
            }
        }

        // ---- photometric channel c ----
        {
            const float* Ic = I0b + c*HW_;
            const int r0 = v0*W_, r1 = r0 + W_;
            const int rm = max(v0-1,0)*W_, rp = min(v0+2,H_-1)*W_;
            float fm0,f00,f10,fp0, fm1,f01,f11,fp1, g0a,g0b,g1a,g1b;
            if (u0 >= 1 && u0 <= W_-3) {
                const f4a A0 = *(const f4a*)(Ic + r0 + u0 - 1);
                const f4a A1 = *(const f4a*)(Ic + r1 + u0 - 1);
                const f2a Bm = *(const f2a*)(Ic + rm + u0);
                const f2a Bp = *(const f2a*)(Ic + rp + u0);
                fm0=A0.x; f00=A0.y; f10=A0.z; fp0=A0.w;
                fm1=A1.x; f01=A1.y; f11=A1.z; fp1=A1.w;
                g0a=Bm.x; g0b=Bm.y; g1a=Bp.x; g1b=Bp.y;
            } else {
                const int um = max(u0-1, 0), up = min(u0+2, W_-1);
                f00=Ic[r0+u0]; f10=Ic[r0+u0+1]; f01=Ic[r1+u0]; f11=Ic[r1+u0+1];
                fm0=Ic[r0+um]; fp0=Ic[r0+up];   fm1=Ic[r1+um]; fp1=Ic[r1+up];
                g0a=Ic[rm+u0]; g0b=Ic[rm+u0+1]; g1a=Ic[rp+u0]; g1b=Ic[rp+u0+1];
            }
            const float I0w = w00*f00 + w10*f10 + w01*f01 + w11*f11;
            const float gx00 = 0.5f*(f10 - fm0);
            const float gx10 = 0.5f*(fp0 - f00);
            const float gx01 = 0.5f*(f11 - fm1);
            const float gx11 = 0.5f*(fp1 - f01);
            const float gy00 = 0.5f*(f01 - g0a);
            const float gy10 = 0.5f*(f11 - g0b);
            const float gy01 = 0.5f*(g1a - f00);
            const float gy11 = 0.5f*(g1b - f10);
            const float gx = w00*gx00 + w10*gx10 + w01*gx01 + w11*gx11;
            const float gy = w00*gy00 + w10*gy10 + w01*gy01 + w11*gy11;
            const float rv = I1b[c*HW_ + p] - I0w;
            float Jr[6];
#pragma unroll
            for (int k = 0; k < 6; k++) Jr[k] = gx*Jw0[k] + gy*Jw1[k];
            const float ar = fabsf(rv);
            const float wt = (ar <= HUBER) ? 1.f : HUBER / fmaxf(ar, 1e-12f);
            int cnt = 0;
#pragma unroll
            for (int i2 = 0; i2 < 6; i2++) {
                const float wJ = wt * Jr[i2];
#pragma unroll
                for (int j2 = i2; j2 < 6; j2++) a[cnt++] += wJ * Jr[j2];
                a[21+i2] += wJ * rv;
            }
        }

        // ---- ICP channel (c==0 items only) ----
        if (c == 0) {
            const f2a D0 = *(const f2a*)(d0b + i00);
            const f2a D1 = *(const f2a*)(d0b + i01);
            const float dc00 = D0.x, dc10 = D0.y, dc01 = D1.x, dc11 = D1.y;
            const float pxu0 = ((float)u0 - cx)*ifx, pxu1 = ((float)(u0+1) - cx)*ifx;
            const float pyv0 = ((float)v0 - cy)*ify, pyv1 = ((float)(v0+1) - cy)*ify;
            const float rVx = w00*pxu0*dc00 + w10*pxu1*dc10 + w01*pxu0*dc01 + w11*pxu1*dc11;
            const float rVy = w00*pyv0*dc00 + w10*pyv0*dc10 + w01*pyv1*dc01 + w11*pyv1*dc11;
            const float rVz = w00*dc00 + w10*dc10 + w01*dc01 + w11*dc11;
            float rN[3];
#pragma unroll
            for (int cc = 0; cc < 3; cc++) {
                const float* Nc = N0b + cc*HW_;
                const f2a Na = *(const f2a*)(Nc + i00);
                const f2a Nb = *(const f2a*)(Nc + i01);
                rN[cc] = w00*Na.x + w10*Na.y + w01*Nb.x + w11*Nb.y;
            }
            const float dfx = X - rVx, dfy = Y - rVy, dfz = Z - rVz;
            const float dn = sqrtf(dfx*dfx + dfy*dfy + dfz*dfz + 1e-12f);
            const bool occ = dn > 0.1f;
            const float res = rN[0]*dfx + rN[1]*dfy + rN[2]*dfz;
            const float NtC0 = rN[0]*R00 + rN[1]*R10 + rN[2]*R20;
            const float NtC1 = rN[0]*R01 + rN[1]*R11 + rN[2]*R21;
            const float NtC2 = rN[0]*R02 + rN[1]*R12 + rN[2]*R22;
            const float Jr0 = NtC1*V1z - NtC2*V1y;
            const float Jr1 = NtC2*V1x - NtC0*V1z;
            const float Jr2 = NtC0*V1y - NtC1*V1x;
            const float sd0 = d1v * (5.5f/525.0f);
            const float sd2 = d1v * d1v * (0.4f/(525.0f*1.2f));
            const float cov = (NtC0*NtC0 + NtC1*NtC1)*sd0*sd0 + NtC2*NtC2*sd2*sd2;
            const float sigma = sqrtf(cov + 1e-8f);
            const float invs = 1.0f/(sigma + 1e-8f);
            const float rZ = occ ? 1e-6f : res*invs;
            float Jr[6];
            Jr[0] = GEOMW * (-Jr0*invs);
            Jr[1] = GEOMW * (-Jr1*invs);
            Jr[2] = GEOMW * (-Jr2*invs);
            Jr[3] = GEOMW * ( NtC0*invs);
            Jr[4] = GEOMW * ( NtC1*invs);
            Jr[5] = GEOMW * ( NtC2*invs);
            const float rv = -GEOMW * rZ;
            const float ar = fabsf(rv);
            const float wt = (ar <= HUBER) ? 1.f : HUBER / fmaxf(ar, 1e-12f);
            int cnt = 0;
#pragma unroll
            for (int i2 = 0; i2 < 6; i2++) {
                const float wJ = wt * Jr[i2];
#pragma unroll
                for (int j2 = i2; j2 < 6; j2++) a[cnt++] += wJ * Jr[j2];
                a[21+i2] += wJ * rv;
            }
        }
    }

    // reduction: wave shuffle -> LDS per wave -> 27 banded atomics per block
    __shared__ float red[4][27];
    const int wid  = threadIdx.x >> 6;
    const int lane = threadIdx.x & 63;
#pragma unroll
    for (int k = 0; k < 27; k++) {
        float val = a[k];
        for (int off = 32; off > 0; off >>= 1)
            val += __shfl_down(val, off, 64);
        if (lane == 0) red[wid][k] = val;
    }
    __syncthreads();
    if (threadIdx.x < 27) {
        const int k = threadIdx.x;
        atomicAdd(&acc[k*64 + b*16 + band],
                  red[0][k] + red[1][k] + red[2][k] + red[3][k]);
    }
}

__global__ void solve_kernel(const float* __restrict__ acc,  // this iter's ACC_IT
                             float* __restrict__ poseb,
                             float* __restrict__ out) {
    int b = threadIdx.x;
    if (b >= B_) return;
    float av[27];
    for (int k = 0; k < 27; k++) {
        const float* s = acc + k*64 + b*16;
        av[k] = ((s[0] + s[1]) + (s[2] + s[3])) + ((s[4] + s[5]) + (s[6] + s[7]));
    }
    float M[6][7];
    {
        int cnt = 0;
        float Hm[6][6];
        for (int i = 0; i < 6; i++)
            for (int j = i; j < 6; j++) { Hm[i][j] = av[cnt]; Hm[j][i] = av[cnt]; cnt++; }
        for (int i = 0; i < 6; i++) {
            for (int j = 0; j < 6; j++) M[i][j] = Hm[i][j];
            M[i][i] += LMEPS;
            M[i][6] = av[21+i];
        }
    }
    for (int k = 0; k < 6; k++) {
        int piv = k; float mx = fabsf(M[k][k]);
        for (int r = k+1; r < 6; r++) { float vv = fabsf(M[r][k]); if (vv > mx) { mx = vv; piv = r; } }
        if (piv != k)
            for (int j = 0; j < 7; j++) { float tmp = M[k][j]; M[k][j] = M[piv][j]; M[piv][j] = tmp; }
        const float inv = 1.0f / M[k][k];
        for (int r = k+1; r < 6; r++) {
            const float f = M[r][k] * inv;
            for (int j = k; j < 7; j++) M[r][j] -= f * M[k][j];
        }
    }
    float xi[6];
    for (int i = 5; i >= 0; i--) {
        float s = M[i][6];
        for (int j = i+1; j < 6; j++) s -= M[i][j]*xi[j];
        xi[i] = s / M[i][i];
    }
    const float wx = xi[0], wy = xi[1], wz = xi[2];
    const float th2 = wx*wx + wy*wy + wz*wz;
    float A, Bc, Cc;
    if (th2 < 1e-8f) {
        A  = 1.f - th2/6.f;
        Bc = 0.5f - th2/24.f;
        Cc = 1.f/6.f - th2/120.f;
    } else {
        const float th = sqrtf(th2);
        const float s = sinf(th), cth = cosf(th);
        A  = s/th;
        Bc = (1.f - cth)/th2;
        Cc = (th - s)/(th2*th);
    }
    float K[3][3] = {{0.f, -wz, wy}, {wz, 0.f, -wx}, {-wy, wx, 0.f}};
    float K2[3][3];
    for (int i = 0; i < 3; i++)
        for (int j = 0; j < 3; j++)
            K2[i][j] = K[i][0]*K[0][j] + K[i][1]*K[1][j] + K[i][2]*K[2][j];
    float Re[3][3], Vm[3][3];
    for (int i = 0; i < 3; i++)
        for (int j = 0; j < 3; j++) {
            const float eye = (i == j) ? 1.f : 0.f;
            Re[i][j] = eye + A*K[i][j] + Bc*K2[i][j];
            Vm[i][j] = eye + Bc*K[i][j] + Cc*K2[i][j];
        }
    float tt[3];
    for (int i = 0; i < 3; i++)
        tt[i] = Vm[i][0]*xi[3] + Vm[i][1]*xi[4] + Vm[i][2]*xi[5];
    float Pold[16], Pnew[16];
    for (int i = 0; i < 16; i++) Pold[i] = poseb[b*16 + i];
    for (int j = 0; j < 4; j++) {
        for (int i = 0; i < 3; i++)
            Pnew[i*4+j] = Re[i][0]*Pold[0*4+j] + Re[i][1]*Pold[1*4+j] + Re[i][2]*Pold[2*4+j] + tt[i]*Pold[3*4+j];
        Pnew[3*4+j] = Pold[3*4+j];
    }
    for (int i = 0; i < 16; i++) { poseb[b*16 + i] = Pnew[i]; out[b*16 + i] = Pnew[i]; }
}

extern "C" void kernel_launch(void* const* d_in, const int* in_sizes, int n_in,
                              void* d_out, int out_size, void* d_ws, size_t ws_size,
                              hipStream_t stream) {
    const float* pose0  = (const float*)d_in[0];
    const float* I0     = (const float*)d_in[1];
    const float* I1     = (const float*)d_in[2];
    const float* intr   = (const float*)d_in[5];
    const float* depth0 = (const float*)d_in[6];
    const float* depth1 = (const float*)d_in[7];
    float* ws    = (float*)d_ws;
    float* N0    = ws;
    float* acc   = ws + N0_SZ;
    float* poseb = acc + ACC_SZ;
    float* out   = (float*)d_out;

    precompute_kernel<<<(B_*HW_ + 255)/256, 256, 0, stream>>>(depth0, intr, pose0, N0, acc, poseb);
    for (int it = 0; it < 3; it++) {
        accumulate_kernel<<<dim3(256, B_), 256, 0, stream>>>(
            I0, I1, depth0, depth1, intr, N0, poseb, acc + it*ACC_IT);
        solve_kernel<<<1, 64, 0, stream>>>(acc + it*ACC_IT, poseb, out);
    }
}